// Round 2
// baseline (18126.675 us; speedup 1.0000x reference)
//
#include <hip/hip_runtime.h>
#include <hip/hip_bf16.h>
#include <hip/hip_cooperative_groups.h>

namespace cg = cooperative_groups;

#define T_DIM 512
#define B_DIM 64
#define U_DIM 1024
#define G_DIM 4128
#define K_DIM 1024
#define CH 64
#define NCHUNK (T_DIM / CH)

typedef __attribute__((ext_vector_type(8))) __bf16 bf16x8;
typedef __attribute__((ext_vector_type(4))) float floatx4;

// column permutation: p<32 -> masters (f:0..15, i:16..31)
// p>=32: p-32 = u*4+g  ->  original col 32 + g*1024 + u   (u = l*64+c)
__device__ __forceinline__ int orig_col(int p) {
  return (p < 32) ? p : (32 + ((p - 32) & 3) * 1024 + ((p - 32) >> 2));
}

// ---------- prep: fp32 [1024][4128] -> bf16 [4128][1024], permuted rows ----------
__global__ __launch_bounds__(256) void transpose_perm_kernel(
    const float* __restrict__ src, __bf16* __restrict__ dst) {
  int idx = blockIdx.x * 256 + threadIdx.x;  // 4128 * 64 threads
  int p = idx >> 6;
  int kc = (idx & 63) << 4;
  int oc = orig_col(p);
  const float* s = src + (size_t)kc * G_DIM + oc;
  __bf16* d = dst + (size_t)p * K_DIM + kc;
#pragma unroll
  for (int j = 0; j < 16; ++j) d[j] = (__bf16)s[(size_t)j * G_DIM];
}

// ---------- GEMM1 chunk: Zxc[tl][b][p] = x[b*512+t0+tl][:] @ Wt[p][:] + bias ----------
__global__ __launch_bounds__(256) void gemm1_kernel(
    const float* __restrict__ x, const __bf16* __restrict__ Wt,
    const float* __restrict__ bias, float* __restrict__ Zxc, int t0) {
  __shared__ __bf16 As[64 * 40];
  __shared__ __bf16 Bs[64 * 40];
  int tid = threadIdx.x;
  int wave = tid >> 6, lane = tid & 63;
  int quad = lane >> 4, ln = lane & 15;
  int b = blockIdx.x;       // one batch row per block.x; 64 t's = 64 M-rows
  int p0 = blockIdx.y * 64;

  int srow = tid >> 2, skc = (tid & 3) << 3;
  const float* ap = x + (size_t)(b * T_DIM + t0 + srow) * K_DIM + skc;
  __bf16* asw = As + srow * 40 + skc;
  bool bval = (p0 + srow) < G_DIM;
  const __bf16* bp = Wt + (size_t)(p0 + srow) * K_DIM + skc;
  __bf16* bsw = Bs + srow * 40 + skc;

  floatx4 acc[4];
#pragma unroll
  for (int n = 0; n < 4; ++n) acc[n] = {0.f, 0.f, 0.f, 0.f};

  const __bf16* afp = As + (wave * 16 + ln) * 40 + (quad << 3);

  for (int k0 = 0; k0 < K_DIM; k0 += 32) {
    __syncthreads();
    float4 a0 = *(const float4*)(ap + k0);
    float4 a1 = *(const float4*)(ap + k0 + 4);
    bf16x8 av;
    av[0] = (__bf16)a0.x; av[1] = (__bf16)a0.y; av[2] = (__bf16)a0.z; av[3] = (__bf16)a0.w;
    av[4] = (__bf16)a1.x; av[5] = (__bf16)a1.y; av[6] = (__bf16)a1.z; av[7] = (__bf16)a1.w;
    *(bf16x8*)asw = av;
    bf16x8 bv;
    if (bval) {
      bv = *(const bf16x8*)(bp + k0);
    } else {
#pragma unroll
      for (int j = 0; j < 8; ++j) bv[j] = (__bf16)0.0f;
    }
    *(bf16x8*)bsw = bv;
    __syncthreads();
    bf16x8 af = *(const bf16x8*)afp;
#pragma unroll
    for (int n = 0; n < 4; ++n) {
      bf16x8 bf = *(const bf16x8*)(Bs + (n * 16 + ln) * 40 + (quad << 3));
      acc[n] = __builtin_amdgcn_mfma_f32_16x16x32_bf16(af, bf, acc[n], 0, 0, 0);
    }
  }
  int tb = wave * 16 + quad * 4;  // local t within chunk
#pragma unroll
  for (int n = 0; n < 4; ++n) {
    int p = p0 + n * 16 + ln;
    if (p < G_DIM) {
      float bz = bias[orig_col(p)];
#pragma unroll
      for (int r = 0; r < 4; ++r) {
        int tl = tb + r;
        Zxc[((size_t)tl * B_DIM + b) * G_DIM + p] = acc[n][r] + bz;
      }
    }
  }
}

// ---------- persistent cooperative recurrence (one chunk of CH steps) ----------
// 256 blocks x 384 thr (6 waves). block = (ub, bh): u in [ub*16, ub*16+16),
// b in [bh*16, bh*16+16). z-tile cols: [0..32)=masters, [32..96)=u_local*4+gate.
// Wave w owns cols [w*16, w*16+16); its Wr slice lives in 128 VGPRs.
#define SMH 1032  // h-tile row stride in bf16 (1024 + 8 pad)

__global__ __launch_bounds__(384, 2) void recur_kernel(
    const float* __restrict__ Zxc, const __bf16* __restrict__ Wrt,
    __bf16* __restrict__ hb, float* __restrict__ cws,
    float* __restrict__ out, int t0) {
  __shared__ __bf16 hsm[16 * SMH];
  __shared__ float zsm[16 * 97];
  cg::grid_group gg = cg::this_grid();

  int tid = threadIdx.x;
  int wave = tid >> 6, lane = tid & 63;
  int quad = lane >> 4, ln = lane & 15;
  int blk = blockIdx.x;
  int ub = blk >> 2, bh = blk & 3;
  int u0 = ub * 16, b0 = bh * 16;

  // B fragments: wave's 16 output cols, full K=1024, resident in registers
  int col = wave * 16 + ln;
  int p = (col < 32) ? col : (32 + u0 * 4 + (col - 32));
  bf16x8 breg[32];
  {
    const __bf16* wrp = Wrt + (size_t)p * K_DIM + (quad << 3);
#pragma unroll
    for (int kk = 0; kk < 32; ++kk) breg[kk] = *(const bf16x8*)(wrp + kk * 32);
  }

  // pointwise mapping (first 256 threads)
  int pb = tid >> 4, pu = tid & 15;
  int u = u0 + pu, gb = b0 + pb;
  int lev = u >> 6;
  float c_reg = (tid < 256) ? cws[gb * U_DIM + u] : 0.f;

  // z staging mapping (all 384 threads, 4 cols each)
  int zpb = tid / 24, zq = tid % 24;
  int cg4 = zq << 2;
  int pz = (cg4 < 32) ? cg4 : (32 + u0 * 4 + (cg4 - 32));

  const char* ar = (const char*)hsm + ln * (SMH * 2) + (quad << 4);

  for (int tl = 0; tl < CH; ++tl) {
    int t = t0 + tl;
    int cur = t & 1;
    // stage h tile [16 rows x 1024] bf16 -> LDS (rows padded to SMH)
    if (tid < 256) {
      const char* hsrc = (const char*)(hb + ((size_t)cur * B_DIM + b0) * U_DIM);
#pragma unroll
      for (int it = 0; it < 8; ++it) {
        int pos = it * 4096 + tid * 16;
        bf16x8 v = *(const bf16x8*)(hsrc + pos);
        *(bf16x8*)((char*)hsm + (pos >> 11) * (SMH * 2) + (pos & 2047)) = v;
      }
    }
    // stage z tile from Zxc (bias already folded)
    {
      const float* zx = Zxc + ((size_t)tl * B_DIM + (b0 + zpb)) * G_DIM + pz;
      float4 zv = *(const float4*)zx;
      float* zw = zsm + zpb * 97 + cg4;
      zw[0] = zv.x; zw[1] = zv.y; zw[2] = zv.z; zw[3] = zv.w;
    }
    __syncthreads();
    // z += h @ WrT : each wave one 16x16 tile over K=1024
    floatx4 acc = {0.f, 0.f, 0.f, 0.f};
#pragma unroll
    for (int kk = 0; kk < 32; ++kk) {
      bf16x8 a = *(const bf16x8*)(ar + kk * 64);
      acc = __builtin_amdgcn_mfma_f32_16x16x32_bf16(a, breg[kk], acc, 0, 0, 0);
    }
#pragma unroll
    for (int r = 0; r < 4; ++r) zsm[(quad * 4 + r) * 97 + col] += acc[r];
    __syncthreads();
    // pointwise ONLSTM update
    if (tid < 256) {
      const float* zrow = zsm + pb * 97;
      float zf[16], zi[16];
#pragma unroll
      for (int j = 0; j < 16; ++j) { zf[j] = zrow[j]; zi[j] = zrow[16 + j]; }
      float mf = zf[0], mi = zi[0];
#pragma unroll
      for (int j = 1; j < 16; ++j) { mf = fmaxf(mf, zf[j]); mi = fmaxf(mi, zi[j]); }
      float sf = 0.f, cf = 0.f, si = 0.f, ci = 0.f;
#pragma unroll
      for (int j = 0; j < 16; ++j) {
        float ef = __expf(zf[j] - mf);
        sf += ef; if (j <= lev) cf += ef;
        float ei = __expf(zi[j] - mi);
        si += ei; if (j >= lev) ci += ei;
      }
      float fm = cf / sf;   // l2r cumsoftmax (inclusive)
      float im = ci / si;   // r2l cumsoftmax (inclusive)
      float ov = fm * im;
      float g0 = zrow[32 + pu * 4 + 0];
      float g1 = zrow[32 + pu * 4 + 1];
      float g2 = zrow[32 + pu * 4 + 2];
      float g3 = zrow[32 + pu * 4 + 3];
      float fg = 1.f / (1.f + __expf(-g0));
      float ig = 1.f / (1.f + __expf(-g1));
      float og = 1.f / (1.f + __expf(-g2));
      float cin = 1.f - 2.f / (1.f + __expf(2.f * g3));
      c_reg = c_reg * (ov * fg + fm - ov) + cin * (ov * ig + im - ov);
      float hv = og * (1.f - 2.f / (1.f + __expf(2.f * c_reg)));
      out[((size_t)gb * T_DIM + t) * U_DIM + u] = hv;
      hb[((size_t)(cur ^ 1) * B_DIM + gb) * U_DIM + u] = (__bf16)hv;
    }
    gg.sync();
  }
  if (tid < 256) cws[gb * U_DIM + u] = c_reg;
}

extern "C" void kernel_launch(void* const* d_in, const int* in_sizes, int n_in,
                              void* d_out, int out_size, void* d_ws, size_t ws_size,
                              hipStream_t stream) {
  const float* x = (const float*)d_in[0];
  const float* W = (const float*)d_in[1];
  const float* Wr = (const float*)d_in[2];
  const float* bias = (const float*)d_in[3];
  float* out = (float*)d_out;

  // ws layout (bytes):
  const size_t ZXC_B = (size_t)CH * B_DIM * G_DIM * 4;   // 67,633,152
  const size_t WT_B = (size_t)G_DIM * K_DIM * 2;          // 8,454,144
  const size_t HB_B = (size_t)2 * B_DIM * U_DIM * 2;      // 262,144
  const size_t CW_B = (size_t)B_DIM * U_DIM * 4;          // 262,144
  const size_t NEED = ZXC_B + 2 * WT_B + HB_B + CW_B;     // ~85.1 MB
  if (ws_size < NEED) return;  // fail gracefully (visible absmax) instead of faulting

  char* ws = (char*)d_ws;
  float* Zxc = (float*)ws;
  __bf16* Wt = (__bf16*)(ws + ZXC_B);
  __bf16* Wrt = (__bf16*)(ws + ZXC_B + WT_B);
  __bf16* hb = (__bf16*)(ws + ZXC_B + 2 * WT_B);
  float* cws = (float*)(ws + ZXC_B + 2 * WT_B + HB_B);

  hipMemsetAsync(hb, 0, HB_B, stream);
  hipMemsetAsync(cws, 0, CW_B, stream);
  transpose_perm_kernel<<<1032, 256, 0, stream>>>(W, Wt);
  transpose_perm_kernel<<<1032, 256, 0, stream>>>(Wr, Wrt);

  for (int c = 0; c < NCHUNK; ++c) {
    int t0 = c * CH;
    gemm1_kernel<<<dim3(64, 65), 256, 0, stream>>>(x, Wt, bias, Zxc, t0);
    void* args[] = {(void*)&Zxc, (void*)&Wrt, (void*)&hb, (void*)&cws,
                    (void*)&out, (void*)&t0};
    hipLaunchCooperativeKernel((void*)recur_kernel, dim3(256), dim3(384), args,
                               0, stream);
  }
}

// Round 3
// 7994.431 us; speedup vs baseline: 2.2674x; 2.2674x over previous
//
#include <hip/hip_runtime.h>
#include <hip/hip_bf16.h>
#include <hip/hip_cooperative_groups.h>

namespace cg = cooperative_groups;

#define T_DIM 512
#define B_DIM 64
#define U_DIM 1024
#define G_DIM 4128
#define K_DIM 1024
#define CH 64
#define NCHUNK (T_DIM / CH)
#define NBLK 256

typedef __attribute__((ext_vector_type(8))) __bf16 bf16x8;
typedef __attribute__((ext_vector_type(4))) float floatx4;

// column permutation: p<32 -> masters (f:0..15, i:16..31)
// p>=32: p-32 = u*4+g  ->  original col 32 + g*1024 + u   (u = l*64+c)
__device__ __forceinline__ int orig_col(int p) {
  return (p < 32) ? p : (32 + ((p - 32) & 3) * 1024 + ((p - 32) >> 2));
}

// ---------- prep: fp32 [1024][4128] -> bf16 [4128][1024], permuted rows ----------
__global__ __launch_bounds__(256) void transpose_perm_kernel(
    const float* __restrict__ src, __bf16* __restrict__ dst) {
  int idx = blockIdx.x * 256 + threadIdx.x;  // 4128 * 64 threads
  int p = idx >> 6;
  int kc = (idx & 63) << 4;
  int oc = orig_col(p);
  const float* s = src + (size_t)kc * G_DIM + oc;
  __bf16* d = dst + (size_t)p * K_DIM + kc;
#pragma unroll
  for (int j = 0; j < 16; ++j) d[j] = (__bf16)s[(size_t)j * G_DIM];
}

// ---------- GEMM1 chunk: Zxc[tl][b][p] = x[b*512+t0+tl][:] @ Wt[p][:] + bias ----------
__global__ __launch_bounds__(256) void gemm1_kernel(
    const float* __restrict__ x, const __bf16* __restrict__ Wt,
    const float* __restrict__ bias, float* __restrict__ Zxc, int t0) {
  __shared__ __bf16 As[64 * 40];
  __shared__ __bf16 Bs[64 * 40];
  int tid = threadIdx.x;
  int wave = tid >> 6, lane = tid & 63;
  int quad = lane >> 4, ln = lane & 15;
  int b = blockIdx.x;
  int p0 = blockIdx.y * 64;

  int srow = tid >> 2, skc = (tid & 3) << 3;
  const float* ap = x + (size_t)(b * T_DIM + t0 + srow) * K_DIM + skc;
  __bf16* asw = As + srow * 40 + skc;
  bool bval = (p0 + srow) < G_DIM;
  const __bf16* bp = Wt + (size_t)(p0 + srow) * K_DIM + skc;
  __bf16* bsw = Bs + srow * 40 + skc;

  floatx4 acc[4];
#pragma unroll
  for (int n = 0; n < 4; ++n) acc[n] = {0.f, 0.f, 0.f, 0.f};

  const __bf16* afp = As + (wave * 16 + ln) * 40 + (quad << 3);

  for (int k0 = 0; k0 < K_DIM; k0 += 32) {
    __syncthreads();
    float4 a0 = *(const float4*)(ap + k0);
    float4 a1 = *(const float4*)(ap + k0 + 4);
    bf16x8 av;
    av[0] = (__bf16)a0.x; av[1] = (__bf16)a0.y; av[2] = (__bf16)a0.z; av[3] = (__bf16)a0.w;
    av[4] = (__bf16)a1.x; av[5] = (__bf16)a1.y; av[6] = (__bf16)a1.z; av[7] = (__bf16)a1.w;
    *(bf16x8*)asw = av;
    bf16x8 bv;
    if (bval) {
      bv = *(const bf16x8*)(bp + k0);
    } else {
#pragma unroll
      for (int j = 0; j < 8; ++j) bv[j] = (__bf16)0.0f;
    }
    *(bf16x8*)bsw = bv;
    __syncthreads();
    bf16x8 af = *(const bf16x8*)afp;
#pragma unroll
    for (int n = 0; n < 4; ++n) {
      bf16x8 bf = *(const bf16x8*)(Bs + (n * 16 + ln) * 40 + (quad << 3));
      acc[n] = __builtin_amdgcn_mfma_f32_16x16x32_bf16(af, bf, acc[n], 0, 0, 0);
    }
  }
  int tb = wave * 16 + quad * 4;
#pragma unroll
  for (int n = 0; n < 4; ++n) {
    int p = p0 + n * 16 + ln;
    if (p < G_DIM) {
      float bz = bias[orig_col(p)];
#pragma unroll
      for (int r = 0; r < 4; ++r) {
        int tl = tb + r;
        Zxc[((size_t)tl * B_DIM + b) * G_DIM + p] = acc[n][r] + bz;
      }
    }
  }
}

// ---------- persistent cooperative recurrence (one chunk of CH steps) ----------
// 256 blocks x 384 thr. block = (ub, bh): u in [ub*16,+16), b in [bh*16,+16).
// Custom flag barrier: flags[blk]=gen (agent scope), wave0 polls all 256.
#define SMH 1032  // h-tile row stride in bf16 (1024 + 8 pad)

__global__ __launch_bounds__(384, 2) void recur_kernel(
    const float* __restrict__ Zxc, const __bf16* __restrict__ Wrt,
    __bf16* __restrict__ hb, float* __restrict__ cws,
    unsigned* __restrict__ flags, float* __restrict__ out, int t0) {
  __shared__ __bf16 hsm[16 * SMH];
  __shared__ float zsm[16 * 97];

  int tid = threadIdx.x;
  int wave = tid >> 6, lane = tid & 63;
  int quad = lane >> 4, ln = lane & 15;
  int blk = blockIdx.x;
  int ub = blk >> 2, bh = blk & 3;
  int u0 = ub * 16, b0 = bh * 16;

  // B fragments: wave's 16 output cols, full K=1024, resident in registers
  int col = wave * 16 + ln;
  int p = (col < 32) ? col : (32 + u0 * 4 + (col - 32));
  bf16x8 breg[32];
  {
    const __bf16* wrp = Wrt + (size_t)p * K_DIM + (quad << 3);
#pragma unroll
    for (int kk = 0; kk < 32; ++kk) breg[kk] = *(const bf16x8*)(wrp + kk * 32);
  }

  // pointwise mapping (first 256 threads)
  int pb = tid >> 4, pu = tid & 15;
  int u = u0 + pu, gb = b0 + pb;
  int lev = u >> 6;
  float c_reg = (tid < 256) ? cws[gb * U_DIM + u] : 0.f;

  // z staging mapping (all 384 threads, 4 cols each)
  int zpb = tid / 24, zq = tid % 24;
  int cg4 = zq << 2;
  int pz = (cg4 < 32) ? cg4 : (32 + u0 * 4 + (cg4 - 32));
  float* zw = zsm + zpb * 97 + cg4;

  const char* ar = (const char*)hsm + ln * (SMH * 2) + (quad << 4);

  // prefetch z for tl = 0
  float4 zpre = *(const float4*)(Zxc + ((size_t)0 * B_DIM + (b0 + zpb)) * G_DIM + pz);

  for (int tl = 0; tl < CH; ++tl) {
    int t = t0 + tl;
    int cur = t & 1;
    // stage h tile [16 x 1024] bf16 -> LDS (plain loads; prev barrier made it visible)
    if (tid < 256) {
      const char* hsrc = (const char*)(hb + ((size_t)cur * B_DIM + b0) * U_DIM);
#pragma unroll
      for (int it = 0; it < 8; ++it) {
        int pos = it * 4096 + tid * 16;
        bf16x8 v = *(const bf16x8*)(hsrc + pos);
        *(bf16x8*)((char*)hsm + (pos >> 11) * (SMH * 2) + (pos & 2047)) = v;
      }
    }
    // commit prefetched z
    zw[0] = zpre.x; zw[1] = zpre.y; zw[2] = zpre.z; zw[3] = zpre.w;
    __syncthreads();
    // z += h @ WrT : each wave one 16x16 tile over K=1024
    floatx4 acc = {0.f, 0.f, 0.f, 0.f};
#pragma unroll
    for (int kk = 0; kk < 32; ++kk) {
      bf16x8 a = *(const bf16x8*)(ar + kk * 64);
      acc = __builtin_amdgcn_mfma_f32_16x16x32_bf16(a, breg[kk], acc, 0, 0, 0);
    }
#pragma unroll
    for (int r = 0; r < 4; ++r) zsm[(quad * 4 + r) * 97 + col] += acc[r];
    __syncthreads();
    // pointwise ONLSTM update
    if (tid < 256) {
      const float* zrow = zsm + pb * 97;
      float zf[16], zi[16];
#pragma unroll
      for (int j = 0; j < 16; ++j) { zf[j] = zrow[j]; zi[j] = zrow[16 + j]; }
      float mf = zf[0], mi = zi[0];
#pragma unroll
      for (int j = 1; j < 16; ++j) { mf = fmaxf(mf, zf[j]); mi = fmaxf(mi, zi[j]); }
      float sf = 0.f, cf = 0.f, si = 0.f, ci = 0.f;
#pragma unroll
      for (int j = 0; j < 16; ++j) {
        float ef = __expf(zf[j] - mf);
        sf += ef; if (j <= lev) cf += ef;
        float ei = __expf(zi[j] - mi);
        si += ei; if (j >= lev) ci += ei;
      }
      float fm = cf / sf;   // l2r cumsoftmax (inclusive)
      float im = ci / si;   // r2l cumsoftmax (inclusive)
      float ov = fm * im;
      float g0 = zrow[32 + pu * 4 + 0];
      float g1 = zrow[32 + pu * 4 + 1];
      float g2 = zrow[32 + pu * 4 + 2];
      float g3 = zrow[32 + pu * 4 + 3];
      float fg = 1.f / (1.f + __expf(-g0));
      float ig = 1.f / (1.f + __expf(-g1));
      float og = 1.f / (1.f + __expf(-g2));
      float cin = 1.f - 2.f / (1.f + __expf(2.f * g3));
      c_reg = c_reg * (ov * fg + fm - ov) + cin * (ov * ig + im - ov);
      float hv = og * (1.f - 2.f / (1.f + __expf(2.f * c_reg)));
      out[((size_t)gb * T_DIM + t) * U_DIM + u] = hv;
      hb[((size_t)(cur ^ 1) * B_DIM + gb) * U_DIM + u] = (__bf16)hv;
    }
    // prefetch z for next step (hides Zx refetch under the barrier)
    if (tl + 1 < CH)
      zpre = *(const float4*)(Zxc + ((size_t)(tl + 1) * B_DIM + (b0 + zpb)) * G_DIM + pz);

    // ---- custom grid barrier, gen = t+1 (monotonic across chunks) ----
    __syncthreads();  // all block stores issued & drained (vmcnt 0 before s_barrier)
    if (tid < 64) {
      __builtin_amdgcn_fence(__ATOMIC_RELEASE, "agent");  // buffer_wbl2: publish h
      if (tid == 0)
        __hip_atomic_store(&flags[blk], (unsigned)(t + 1), __ATOMIC_RELAXED,
                           __HIP_MEMORY_SCOPE_AGENT);
      unsigned gen = (unsigned)(t + 1);
      for (;;) {
        bool ok = true;
#pragma unroll
        for (int j = 0; j < 4; ++j) {
          unsigned v = __hip_atomic_load(&flags[lane + 64 * j], __ATOMIC_RELAXED,
                                         __HIP_MEMORY_SCOPE_AGENT);
          ok &= (v >= gen);
        }
        if (__all(ok)) break;
      }
      __builtin_amdgcn_fence(__ATOMIC_ACQUIRE, "agent");  // buffer_inv: see new h
    }
    __syncthreads();
  }
  if (tid < 256) cws[gb * U_DIM + u] = c_reg;
}

extern "C" void kernel_launch(void* const* d_in, const int* in_sizes, int n_in,
                              void* d_out, int out_size, void* d_ws, size_t ws_size,
                              hipStream_t stream) {
  const float* x = (const float*)d_in[0];
  const float* W = (const float*)d_in[1];
  const float* Wr = (const float*)d_in[2];
  const float* bias = (const float*)d_in[3];
  float* out = (float*)d_out;

  const size_t ZXC_B = (size_t)CH * B_DIM * G_DIM * 4;   // 67,633,152
  const size_t WT_B = (size_t)G_DIM * K_DIM * 2;          // 8,454,144
  const size_t HB_B = (size_t)2 * B_DIM * U_DIM * 2;      // 262,144
  const size_t CW_B = (size_t)B_DIM * U_DIM * 4;          // 262,144
  const size_t FL_B = 4096;
  const size_t NEED = ZXC_B + 2 * WT_B + HB_B + CW_B + FL_B;  // ~85.1 MB
  if (ws_size < NEED) return;

  char* ws = (char*)d_ws;
  float* Zxc = (float*)ws;
  __bf16* Wt = (__bf16*)(ws + ZXC_B);
  __bf16* Wrt = (__bf16*)(ws + ZXC_B + WT_B);
  __bf16* hb = (__bf16*)(ws + ZXC_B + 2 * WT_B);
  float* cws = (float*)(ws + ZXC_B + 2 * WT_B + HB_B);
  unsigned* flags = (unsigned*)(ws + ZXC_B + 2 * WT_B + HB_B + CW_B);

  hipMemsetAsync(hb, 0, HB_B, stream);
  hipMemsetAsync(cws, 0, CW_B, stream);
  hipMemsetAsync(flags, 0, FL_B, stream);
  transpose_perm_kernel<<<1032, 256, 0, stream>>>(W, Wt);
  transpose_perm_kernel<<<1032, 256, 0, stream>>>(Wr, Wrt);

  for (int c = 0; c < NCHUNK; ++c) {
    int t0 = c * CH;
    gemm1_kernel<<<dim3(64, 65), 256, 0, stream>>>(x, Wt, bias, Zxc, t0);
    void* args[] = {(void*)&Zxc, (void*)&Wrt, (void*)&hb, (void*)&cws,
                    (void*)&flags, (void*)&out, (void*)&t0};
    hipLaunchCooperativeKernel((void*)recur_kernel, dim3(NBLK), dim3(384), args,
                               0, stream);
  }
}